// Round 1
// 619.927 us; speedup vs baseline: 1.0100x; 1.0100x over previous
//
#include <hip/hip_runtime.h>
#include <hip/hip_bf16.h>
#include <math.h>

typedef __hip_bfloat16 bf16;
typedef float f32x4 __attribute__((ext_vector_type(4)));  // native vec for nt-store

#define BATCH    8
#define DIM      128
#define NFRAMES  128
#define NSAMP    32768
#define NTAB     16
#define TSIZE    512

// dual-dtype input loader (inputs measured fp32; bf16 hedge kept).
__device__ __forceinline__ float ld(const void* p, int i, bool f32) {
    return f32 ? ((const float*)p)[i] : __bfloat162float(((const bf16*)p)[i]);
}

// workspace layout (float element offsets) — offsets kept from previous version
#define WS_VALUES 0        // 8 floats
#define WS_ENV    64       // 8*128 env^2 frames
#define WS_FREQ   1088     // 8*128 freq^2 frames (NEW: consumed by kB)
#define WS_SEL    2112     // 8*512 normalized selected tables
#define WS_PHASE  6208     // NEW: per-batch f64 segment prefix D[129] (8*258 floats)

// ---------------------------------------------------------------------------
// KA: fused heads. One block per batch item (8 blocks x 512 thr).
// All three MLPs (f64 acc), tc argmax + wavetable norm, env^2 frames,
// freq^2 frames, then a 128-entry f64 frame-prefix D[] for analytic phase.
// The 32768-sample scan is GONE: freq is piecewise-linear on a uniform grid,
// so the cumsum is closed-form per segment (arithmetic series).
// ---------------------------------------------------------------------------
__global__ __launch_bounds__(512) void kA_prep(
    const void* __restrict__ x, const void* __restrict__ wav,
    const void* tw1, const void* tb1, const void* tw2, const void* tb2,
    const void* tw3, const void* tb3,
    const void* ew1, const void* eb1, const void* ew2, const void* eb2,
    const void* ew3, const void* eb3,
    const void* fw1, const void* fb1, const void* fw2, const void* fb2,
    const void* fw3, const void* fb3,
    float* __restrict__ ws)
{
    const int b   = blockIdx.x;
    const int tid = threadIdx.x;

    __shared__ int    s_isf32;
    __shared__ float  xs[DIM];
    __shared__ float  h1s[3][DIM];
    __shared__ float  h2s[3][DIM];
    __shared__ float  o3tc[256];
    __shared__ float  envf[NFRAMES];
    __shared__ float  frf[NFRAMES];
    __shared__ float  scores[16];
    __shared__ float  red[512];
    __shared__ int    s_idx;

    // dtype detect: genuine bf16 N(0,1) never has |v|>=32; fp32 bits misread
    // as bf16 do with overwhelming probability. 512 thr x 2 shorts = same
    // 1024-short coverage as before.
    if (tid == 0) s_isf32 = 0;
    __syncthreads();
    {
        const unsigned short* xb = (const unsigned short*)x;
        const int e0 = (xb[tid] >> 7) & 0xFF;
        const int e1 = (xb[tid + 512] >> 7) & 0xFF;
        if (e0 >= 132 || e1 >= 132) s_isf32 = 1;   // benign race
    }
    __syncthreads();
    const bool F32 = (s_isf32 != 0);

    if (tid < DIM) xs[tid] = ld(x, b*DIM + tid, F32);
    __syncthreads();

    const void* W1h[3] = {tw1, ew1, fw1};
    const void* B1h[3] = {tb1, eb1, fb1};
    const void* W2h[3] = {tw2, ew2, fw2};
    const void* B2h[3] = {tb2, eb2, fb2};

    // ---- layer 1, all heads in parallel (384 threads) ----
    if (tid < 384) {
        const int head = tid >> 7, o = tid & 127;
        double acc = (double)ld(B1h[head], o, F32);
        const void* W = W1h[head];
        for (int k = 0; k < DIM; k++)
            acc += (double)xs[k] * (double)ld(W, k*DIM + o, F32);
        float v = (float)acc;
        h1s[head][o] = v > 0.f ? v : 0.2f*v;
    }
    __syncthreads();

    // ---- layer 2 ----
    if (tid < 384) {
        const int head = tid >> 7, o = tid & 127;
        double acc = (double)ld(B2h[head], o, F32);
        const void* W = W2h[head];
        const float* hh = h1s[head];
        for (int k = 0; k < DIM; k++)
            acc += (double)hh[k] * (double)ld(W, k*DIM + o, F32);
        float v = (float)acc;
        h2s[head][o] = v > 0.f ? v : 0.2f*v;
    }
    __syncthreads();

    // ---- layer 3 (tc: 256 outs, env/freq: 128 each; squared at write) ----
    if (tid < 256) {
        const int o = tid;
        double acc = (double)ld(tb3, o, F32);
        const float* hh = h2s[0];
        for (int k = 0; k < DIM; k++)
            acc += (double)hh[k] * (double)ld(tw3, k*256 + o, F32);
        o3tc[o] = (float)acc;
    } else if (tid < 384) {
        const int o = tid - 256;
        double acc = (double)ld(eb3, o, F32);
        const float* hh = h2s[1];
        for (int k = 0; k < DIM; k++)
            acc += (double)hh[k] * (double)ld(ew3, k*DIM + o, F32);
        const float v = (float)acc;
        envf[o] = v * v;                 // square BEFORE interpolation
    } else if (tid < 512) {
        const int o = tid - 384;
        double acc = (double)ld(fb3, o, F32);
        const float* hh = h2s[2];
        for (int k = 0; k < DIM; k++)
            acc += (double)hh[k] * (double)ld(fw3, k*DIM + o, F32);
        const float v = (float)acc;
        frf[o] = v * v;
    }
    __syncthreads();

    // ---- tc scores -> argmax ----
    if (tid < 16) {
        float s = 0.f;
        for (int j = 0; j < 16; j++) s += o3tc[tid*16 + j];
        scores[tid] = s * (1.0f/16.0f);
    }
    __syncthreads();
    if (tid == 0) {
        float best = scores[0]; int bi = 0;
        for (int i = 1; i < 16; i++)
            if (scores[i] > best) { best = scores[i]; bi = i; }  // first-max
        s_idx = bi;
        ws[WS_VALUES + b] = best;
    }
    __syncthreads();

    // ---- normalized selected wavetable ----
    const int idx = s_idx;
    float wv_t = 0.f;
    if (tid < 512) { wv_t = ld(wav, idx*TSIZE + tid, F32); red[tid] = wv_t; }
    __syncthreads();
    for (int off = 256; off; off >>= 1) {
        if (tid < off) red[tid] = fmaxf(red[tid], red[tid + off]);
        __syncthreads();
    }
    const float mx = red[0] + 1e-8f;
    if (tid < 512) ws[WS_SEL + b*TSIZE + tid] = wv_t / mx;
    if (tid < NFRAMES) {
        ws[WS_ENV  + b*NFRAMES + tid] = envf[tid];
        ws[WS_FREQ + b*NFRAMES + tid] = frf[tid];
    }
    __syncthreads();

    // ---- analytic phase prefix ----
    // Sample->freq mapping (torch interp, align_corners=False, 128->32768):
    //   s in [0,127]        : f = frf[0]                     (clamped, w=0)
    //   s in [128+256m, 383+256m], m=0..126 :
    //       f = frf[m] + (frf[m+1]-frf[m]) * (i+0.5)/256,  i = s-128-256m
    //   s in [32640,32767]  : f = frf[127]                   (clamped)
    // D[m] = inclusive cumsum through s = 127+256m (f64, exact-closed-form
    // equal to the previous sequential f64 scan to ~1e-13).
    if (tid == 0) {
        double* D = (double*)(ws + WS_PHASE) + (size_t)b * 129;
        double run = 128.0 * (double)frf[0];
        D[0] = run;
        for (int m = 0; m < 127; m++) {
            run += 128.0 * ((double)frf[m] + (double)frf[m+1]);
            D[m+1] = run;
        }
    }
}

// ---------------------------------------------------------------------------
// KB: one wave per 8 consecutive rows. Table fragment (2 x f32x4/lane)
// hoisted across rows; phase computed analytically per row (wave-uniform f64,
// O(1) via segment prefix — no phase buffer round-trip); z grid term hoisted
// per lane; nontemporal dwordx4 stores (write-once 512 MiB stream).
// ---------------------------------------------------------------------------
__global__ __launch_bounds__(256) void kB_synth(const float* __restrict__ ws,
                                                float* __restrict__ out)
{
    const int lane = threadIdx.x & 63;
    const int w    = (blockIdx.x << 2) + (threadIdx.x >> 6);
    const int r0   = w << 3;                 // 8 rows, never crosses batch
    const int b    = r0 >> 15;

    const float* tab = ws + WS_SEL + b*TSIZE;
    const f32x4 tv0 = *reinterpret_cast<const f32x4*>(tab + 4*lane);
    const f32x4 tv1 = *reinterpret_cast<const f32x4*>(tab + 4*lane + 256);
    const float  val  = ws[WS_VALUES + b];
    const float* envf = ws + WS_ENV  + b*NFRAMES;
    const float* frq  = ws + WS_FREQ + b*NFRAMES;
    const double* D   = (const double*)(ws + WS_PHASE) + (size_t)b * 129;
    const double f0   = (double)frq[0];
    const double f127 = (double)frq[127];
    float* kbase = out + (size_t)BATCH*NSAMP + ((size_t)r0 << 9);

    // z = (grid[t] - p)/STD = t*(100/511) - 100p : hoist t-term per lane.
    const float KS = 100.0f / 511.0f;
    float zb0[4], zb1[4];
    #pragma unroll
    for (int k = 0; k < 4; k++) {
        zb0[k] = (float)(4*lane + k)       * KS;
        zb1[k] = (float)(4*lane + 256 + k) * KS;
    }

    float samp[8];
    #pragma unroll
    for (int i = 0; i < 8; i++) {
        const int r = r0 + i;
        const int s = r & (NSAMP - 1);

        // ---- analytic inclusive cumsum (wave-uniform branches) ----
        double run;
        if (s < 128) {
            run = (double)(s + 1) * f0;
        } else if (s >= 32640) {
            run = D[127] + (double)(s - 32639) * f127;
        } else {
            const int m = (s - 128) >> 8;
            const int n = ((s - 128) & 255) + 1;
            const double a  = (double)frq[m];
            const double bb = (double)frq[m + 1];
            // sum_{i<n} [a + (bb-a)(i+0.5)/256] = n*a + (bb-a)*n^2/512
            run = D[m] + (double)n * a + (bb - a) * ((double)(n * n) * (1.0 / 512.0));
        }
        const float poff = (float)(-100.0 * (run - floor(run)));   // -100*phase

        // ---- env interp (identical mapping) ----
        float pos = ((float)s + 0.5f) * (1.0f/256.0f) - 0.5f;
        pos = fminf(fmaxf(pos, 0.0f), 127.0f);
        const int lo = (int)pos;
        int hi = lo + 1; if (hi > 127) hi = 127;
        const float wq = pos - (float)lo;
        const float env = envf[lo]*(1.0f - wq) + envf[hi]*wq;

        float dot = 0.f;
        #pragma unroll
        for (int j = 0; j < 2; j++) {
            const int t0 = 4*lane + 256*j;
            const f32x4 tv = j ? tv1 : tv0;
            f32x4 o4;
            #pragma unroll
            for (int k = 0; k < 4; k++) {
                const float z = (j ? zb1[k] : zb0[k]) + poff;
                const float e = __expf(-0.5f*z*z) * 39.89422804014327f;
                dot += e * tv[k];
                o4[k] = e;
            }
            __builtin_nontemporal_store(o4,
                reinterpret_cast<f32x4*>(kbase + (i << 9) + t0));
        }

        #pragma unroll
        for (int m2 = 32; m2; m2 >>= 1) dot += __shfl_xor(dot, m2, 64);
        samp[i] = dot * env * val;           // all lanes hold the full sum
    }

    if (lane == 0) {
        f32x4 a4, b4;
        #pragma unroll
        for (int k = 0; k < 4; k++) { a4[k] = samp[k]; b4[k] = samp[4+k]; }
        *reinterpret_cast<f32x4*>(out + r0)     = a4;   // r0 % 8 == 0 -> aligned
        *reinterpret_cast<f32x4*>(out + r0 + 4) = b4;
    }
}

// ---------------------------------------------------------------------------
extern "C" void kernel_launch(void* const* d_in, const int* in_sizes, int n_in,
                              void* d_out, int out_size, void* d_ws, size_t ws_size,
                              hipStream_t stream)
{
    float* ws  = (float*)d_ws;
    float* out = (float*)d_out;   // fp32 outputs per reference dtype

    hipLaunchKernelGGL(kA_prep, dim3(BATCH), dim3(512), 0, stream,
        d_in[0], d_in[1],
        d_in[2],  d_in[3],  d_in[4],  d_in[5],  d_in[6],  d_in[7],
        d_in[8],  d_in[9],  d_in[10], d_in[11], d_in[12], d_in[13],
        d_in[14], d_in[15], d_in[16], d_in[17], d_in[18], d_in[19],
        ws);

    // 262144 rows / (8 rows/wave * 4 waves/block) = 8192 blocks
    hipLaunchKernelGGL(kB_synth, dim3((BATCH*NSAMP)/32), dim3(256), 0, stream,
        ws, out);
}